// Round 1
// 605.448 us; speedup vs baseline: 6.1335x; 6.1335x over previous
//
#include <hip/hip_runtime.h>
#include <hip/hip_bf16.h>

#define D 128
typedef __hip_bfloat16 bf16;
typedef __hip_bfloat162 bf162;

// ================= dtype probes =================
// flags[0]: 1 if float inputs are f32, 0 if bf16
// flags[1]: 1 if edge_index is int64, 0 if int32
__global__ void probe_float_kernel(const void* __restrict__ x, int* __restrict__ flags) {
    __shared__ int cnt;
    if (threadIdx.x == 0) cnt = 0;
    __syncthreads();
    const unsigned short* u = (const unsigned short*)x;
    int bad = 0;
    // low 16 bits of each 32-bit word: valid bf16 (element 2i) if data is bf16,
    // mantissa junk if data is f32
    for (int i = threadIdx.x; i < 2048; i += blockDim.x) {
        unsigned short v = u[2 * i];
        int e = (v >> 7) & 0xFF;
        if (e == 255 || (e != 0 && (e < 90 || e > 165))) bad++;
    }
    atomicAdd(&cnt, bad);
    __syncthreads();
    if (threadIdx.x == 0) flags[0] = (cnt > 256) ? 1 : 0;
}

__global__ void probe_int_kernel(const void* __restrict__ ei, int* __restrict__ flags) {
    __shared__ int cnt;
    if (threadIdx.x == 0) cnt = 0;
    __syncthreads();
    const int* w = (const int*)ei;
    int nz = 0;
    // odd 32-bit words are all zero iff data is int64 (values < 2^31, nonneg)
    for (int i = threadIdx.x; i < 512; i += blockDim.x) {
        if (w[2 * i + 1] != 0) nz++;
    }
    atomicAdd(&cnt, nz);
    __syncthreads();
    if (threadIdx.x == 0) flags[1] = (cnt == 0) ? 1 : 0;
}

// ================= helpers =================
__device__ __forceinline__ int load_idx(const void* ei, long long pos, int is64) {
    if (is64) return (int)((const long long*)ei)[pos];
    return ((const int*)ei)[pos];
}

// ================= degree =================
__global__ void degree_kernel(const void* __restrict__ ei, float* __restrict__ deg,
                              int E, const int* __restrict__ flags) {
    int e = blockIdx.x * blockDim.x + threadIdx.x;
    if (e >= E) return;
    int c = load_idx(ei, (long long)E + e, flags[1]);  // col = dest
    atomicAdd(&deg[c], 1.0f);
}

__global__ void dinv_kernel(const float* __restrict__ deg, float* __restrict__ dinv, int n) {
    int i = blockIdx.x * blockDim.x + threadIdx.x;
    if (i < n) dinv[i] = rsqrtf(deg[i] + 1.0f);
}

// ================= h = x @ W, stored as bf16 =================
// f32 path:  h -> ws buf0 (bf16), acc will be d_out (f32)
// bf16 path: h -> d_out (bf16), acc will be ws buf0 (f32)
__global__ void gemm_kernel(const void* __restrict__ x, const void* __restrict__ W,
                            void* d_out, float* buf0, const int* __restrict__ flags) {
    __shared__ float xs[D];
    const int r = blockIdx.x;
    const int t = threadIdx.x;  // 0..63
    const int f = flags[0];

    if (f) {  // f32 inputs
        const float2* xr = (const float2*)((const float*)x + (size_t)r * D);
        float2 v = xr[t];
        xs[2 * t] = v.x; xs[2 * t + 1] = v.y;
    } else {
        const bf162* xr = (const bf162*)((const bf16*)x + (size_t)r * D);
        bf162 v = xr[t];
        xs[2 * t] = __bfloat162float(v.x); xs[2 * t + 1] = __bfloat162float(v.y);
    }
    __syncthreads();

    float a0 = 0.f, a1 = 0.f;
    if (f) {
        const float2* W2 = (const float2*)W;
#pragma unroll 8
        for (int k = 0; k < D; ++k) {
            float xk = xs[k];
            float2 wb = W2[k * 64 + t];
            a0 += xk * wb.x; a1 += xk * wb.y;
        }
    } else {
        const bf162* W2 = (const bf162*)W;
#pragma unroll 8
        for (int k = 0; k < D; ++k) {
            float xk = xs[k];
            bf162 wb = W2[k * 64 + t];
            a0 += xk * __bfloat162float(wb.x); a1 += xk * __bfloat162float(wb.y);
        }
    }
    bf16* hdst = f ? (bf16*)buf0 : (bf16*)d_out;
    bf162* hp = (bf162*)hdst;
    bf162 o; o.x = __float2bfloat16(a0); o.y = __float2bfloat16(a1);
    hp[(size_t)r * 64 + t] = o;
}

// ================= acc[i] = dinv^2 * h[i] (self loop, non-atomic init) =====
__global__ void self_init_kernel(float* buf0, void* d_out, const float* __restrict__ dinv,
                                 int total, const int* __restrict__ flags) {
    int gid = blockIdx.x * blockDim.x + threadIdx.x;
    if (gid >= total) return;
    const int f = flags[0];
    const bf16* h = f ? (const bf16*)buf0 : (const bf16*)d_out;
    float* acc = f ? (float*)d_out : buf0;
    float dv = dinv[gid >> 7];
    acc[gid] = dv * dv * __bfloat162float(h[gid]);
}

// ================= edge scatter: acc[col] += norm * h[row] =================
__global__ void scatter_kernel(const void* __restrict__ ei, const float* __restrict__ dinv,
                               float* buf0, void* d_out, int E, const int* __restrict__ flags) {
    int e = blockIdx.x * 2 + (threadIdx.x >> 7);
    int c = threadIdx.x & (D - 1);
    if (e >= E) return;
    const int f = flags[0];
    const int i64 = flags[1];
    int s = load_idx(ei, e, i64);
    int d = load_idx(ei, (long long)E + e, i64);
    const bf16* h = f ? (const bf16*)buf0 : (const bf16*)d_out;
    float* acc = f ? (float*)d_out : buf0;
    float nrm = dinv[s] * dinv[d];
    float v = nrm * __bfloat162float(h[(size_t)s * D + c]);
    atomicAdd(&acc[(size_t)d * D + c], v);
}

// ================= out = acc + b =================
__global__ void finalize_kernel(float* buf0, const void* __restrict__ b, void* d_out,
                                int total, const int* __restrict__ flags) {
    int gid = blockIdx.x * blockDim.x + threadIdx.x;
    if (gid >= total) return;
    const int f = flags[0];
    const int c = gid & (D - 1);
    if (f) {
        float* acc = (float*)d_out;
        float bias = ((const float*)b)[c];
        acc[gid] = acc[gid] + bias;  // in-place, output stays f32
    } else {
        float v = buf0[gid] + __bfloat162float(((const bf16*)b)[c]);
        ((bf16*)d_out)[gid] = __float2bfloat16(v);
    }
}

extern "C" void kernel_launch(void* const* d_in, const int* in_sizes, int n_in,
                              void* d_out, int out_size, void* d_ws, size_t ws_size,
                              hipStream_t stream) {
    const void* x = d_in[0];
    const void* ei = d_in[1];
    const void* W = d_in[2];
    const void* b = d_in[3];

    const int n = in_sizes[0] / D;   // 50000
    const int E = in_sizes[1] / 2;   // 600000

    // ws layout: [buf0: N*D f32 = 25.6MB][deg: N f32][dinv: N f32][flags: 2 int]
    float* buf0 = (float*)d_ws;
    float* deg  = buf0 + (size_t)n * D;
    float* dinv = deg + n;
    int* flags  = (int*)(dinv + n);

    probe_float_kernel<<<1, 256, 0, stream>>>(x, flags);
    probe_int_kernel<<<1, 256, 0, stream>>>(ei, flags);

    hipMemsetAsync(deg, 0, (size_t)n * sizeof(float), stream);
    degree_kernel<<<(E + 255) / 256, 256, 0, stream>>>(ei, deg, E, flags);
    dinv_kernel<<<(n + 255) / 256, 256, 0, stream>>>(deg, dinv, n);
    gemm_kernel<<<n, 64, 0, stream>>>(x, W, d_out, buf0, flags);
    self_init_kernel<<<(n * D + 255) / 256, 256, 0, stream>>>(buf0, d_out, dinv, n * D, flags);
    scatter_kernel<<<(E + 1) / 2, 256, 0, stream>>>(ei, dinv, buf0, d_out, E, flags);
    finalize_kernel<<<(n * D + 255) / 256, 256, 0, stream>>>(buf0, b, d_out, n * D, flags);
}

// Round 2
// 392.211 us; speedup vs baseline: 9.4681x; 1.5437x over previous
//
#include <hip/hip_runtime.h>
#include <hip/hip_bf16.h>

#define D 128
typedef __hip_bfloat16 bf16;
typedef __hip_bfloat162 bf162;

// ================= dtype probes =================
// flags[0]: 1 if float inputs are f32, 0 if bf16
// flags[1]: 1 if edge_index is int64, 0 if int32
__global__ void probe_float_kernel(const void* __restrict__ x, int* __restrict__ flags) {
    __shared__ int cnt;
    if (threadIdx.x == 0) cnt = 0;
    __syncthreads();
    const unsigned short* u = (const unsigned short*)x;
    int bad = 0;
    for (int i = threadIdx.x; i < 2048; i += blockDim.x) {
        unsigned short v = u[2 * i];
        int e = (v >> 7) & 0xFF;
        if (e == 255 || (e != 0 && (e < 90 || e > 165))) bad++;
    }
    atomicAdd(&cnt, bad);
    __syncthreads();
    if (threadIdx.x == 0) flags[0] = (cnt > 256) ? 1 : 0;
}

__global__ void probe_int_kernel(const void* __restrict__ ei, int* __restrict__ flags) {
    __shared__ int cnt;
    if (threadIdx.x == 0) cnt = 0;
    __syncthreads();
    const int* w = (const int*)ei;
    int nz = 0;
    for (int i = threadIdx.x; i < 512; i += blockDim.x) {
        if (w[2 * i + 1] != 0) nz++;
    }
    atomicAdd(&cnt, nz);
    __syncthreads();
    if (threadIdx.x == 0) flags[1] = (cnt == 0) ? 1 : 0;
}

// ================= helpers =================
__device__ __forceinline__ int load_idx(const void* ei, long long pos, int is64) {
    if (is64) return (int)((const long long*)ei)[pos];
    return ((const int*)ei)[pos];
}

// ================= degree (in-degree over real edges; self-loop added as +1) =====
__global__ void degree_kernel(const void* __restrict__ ei, int* __restrict__ deg,
                              int E, const int* __restrict__ flags) {
    int e = blockIdx.x * blockDim.x + threadIdx.x;
    if (e >= E) return;
    int c = load_idx(ei, (long long)E + e, flags[1]);  // col = dest
    atomicAdd(&deg[c], 1);
}

__global__ void dinv_kernel(const int* __restrict__ deg, float* __restrict__ dinv, int n) {
    int i = blockIdx.x * blockDim.x + threadIdx.x;
    if (i < n) dinv[i] = rsqrtf((float)deg[i] + 1.0f);
}

// ================= CSR offsets via per-wave scan + one atomic per wave =========
// Destination ordering in the CSR slab is arbitrary (non-deterministic bases),
// which is fine: we only need disjoint ranges per destination.
__global__ void offsets_kernel(const int* __restrict__ deg, int* __restrict__ off,
                               int* __restrict__ cur, int* __restrict__ counter, int n) {
    int i = blockIdx.x * blockDim.x + threadIdx.x;
    int lane = threadIdx.x & 63;
    int v = (i < n) ? deg[i] : 0;
    int s = v;
#pragma unroll
    for (int dlt = 1; dlt < 64; dlt <<= 1) {
        int t = __shfl_up(s, dlt, 64);
        if (lane >= dlt) s += t;
    }
    int tot = __shfl(s, 63, 64);
    int base = 0;
    if (lane == 0) base = atomicAdd(counter, tot);
    base = __shfl(base, 0, 64);
    if (i < n) {
        int o = base + s - v;  // exclusive prefix within wave
        off[i] = o;
        cur[i] = o;
    }
}

// ================= CSR fill: slot <- (src, dinv[src]) ==========================
__global__ void fill_kernel(const void* __restrict__ ei, const float* __restrict__ dinv,
                            int* __restrict__ cur, int* __restrict__ srcs,
                            float* __restrict__ sdinv, int E, const int* __restrict__ flags) {
    int e = blockIdx.x * blockDim.x + threadIdx.x;
    if (e >= E) return;
    const int i64 = flags[1];
    int s = load_idx(ei, e, i64);
    int d = load_idx(ei, (long long)E + e, i64);
    int pos = atomicAdd(&cur[d], 1);
    srcs[pos] = s;
    sdinv[pos] = dinv[s];
}

// ================= h = x @ W, stored as bf16 in workspace ======================
__global__ void gemm_kernel(const void* __restrict__ x, const void* __restrict__ W,
                            bf16* __restrict__ hbuf, const int* __restrict__ flags) {
    __shared__ float xs[D];
    const int r = blockIdx.x;
    const int t = threadIdx.x;  // 0..63
    const int f = flags[0];

    if (f) {  // f32 inputs
        const float2* xr = (const float2*)((const float*)x + (size_t)r * D);
        float2 v = xr[t];
        xs[2 * t] = v.x; xs[2 * t + 1] = v.y;
    } else {
        const bf162* xr = (const bf162*)((const bf16*)x + (size_t)r * D);
        bf162 v = xr[t];
        xs[2 * t] = __bfloat162float(v.x); xs[2 * t + 1] = __bfloat162float(v.y);
    }
    __syncthreads();

    float a0 = 0.f, a1 = 0.f;
    if (f) {
        const float2* W2 = (const float2*)W;
#pragma unroll 8
        for (int k = 0; k < D; ++k) {
            float xk = xs[k];
            float2 wb = W2[k * 64 + t];
            a0 += xk * wb.x; a1 += xk * wb.y;
        }
    } else {
        const bf162* W2 = (const bf162*)W;
#pragma unroll 8
        for (int k = 0; k < D; ++k) {
            float xk = xs[k];
            bf162 wb = W2[k * 64 + t];
            a0 += xk * __bfloat162float(wb.x); a1 += xk * __bfloat162float(wb.y);
        }
    }
    bf162* hp = (bf162*)hbuf;
    bf162 o; o.x = __float2bfloat16(a0); o.y = __float2bfloat16(a1);
    hp[(size_t)r * 64 + t] = o;
}

// ================= gather: out[d] = sum_in norm*h[s] + dinv^2*h[d] + b =========
// One wave per destination; lane owns columns (2*lane, 2*lane+1).
__global__ void gather_kernel(const bf16* __restrict__ hbuf, const int* __restrict__ off,
                              const int* __restrict__ deg, const int* __restrict__ srcs,
                              const float* __restrict__ sdinv, const float* __restrict__ dinv,
                              const void* __restrict__ b, void* __restrict__ out,
                              int n, const int* __restrict__ flags) {
    int wave = threadIdx.x >> 6;              // 0..3
    int lane = threadIdx.x & 63;
    int d = blockIdx.x * 4 + wave;
    if (d >= n) return;

    const bf162* h2 = (const bf162*)hbuf;
    float dd = dinv[d];
    int start = off[d];
    int len = deg[d];

    float a0 = 0.f, a1 = 0.f;
    for (int base = 0; base < len; base += 64) {
        int m = len - base; if (m > 64) m = 64;
        int sreg = 0; float nreg = 0.f;
        if (lane < m) {
            sreg = srcs[start + base + lane];
            nreg = sdinv[start + base + lane];
        }
        for (int k = 0; k < m; ++k) {
            int s = __shfl(sreg, k, 64);
            float nd = __shfl(nreg, k, 64) * dd;
            bf162 hv = h2[(size_t)s * 64 + lane];
            a0 += nd * __bfloat162float(hv.x);
            a1 += nd * __bfloat162float(hv.y);
        }
    }
    // self loop
    bf162 hs = h2[(size_t)d * 64 + lane];
    float dd2 = dd * dd;
    a0 += dd2 * __bfloat162float(hs.x);
    a1 += dd2 * __bfloat162float(hs.y);

    if (flags[0]) {
        float2 bb = ((const float2*)b)[lane];
        float2 o; o.x = a0 + bb.x; o.y = a1 + bb.y;
        ((float2*)out)[(size_t)d * 64 + lane] = o;
    } else {
        bf162 bb = ((const bf162*)b)[lane];
        bf162 o;
        o.x = __float2bfloat16(a0 + __bfloat162float(bb.x));
        o.y = __float2bfloat16(a1 + __bfloat162float(bb.y));
        ((bf162*)out)[(size_t)d * 64 + lane] = o;
    }
}

extern "C" void kernel_launch(void* const* d_in, const int* in_sizes, int n_in,
                              void* d_out, int out_size, void* d_ws, size_t ws_size,
                              hipStream_t stream) {
    const void* x = d_in[0];
    const void* ei = d_in[1];
    const void* W = d_in[2];
    const void* b = d_in[3];

    const int n = in_sizes[0] / D;   // 50000 rows (f32 path; bf16 path would be 2x but probe handles math)
    const int E = in_sizes[1] / 2;   // 600000 edges (int64 path)

    // ws layout
    bf16*  hbuf    = (bf16*)d_ws;                       // N*D bf16 = 12.8MB
    float* dinv    = (float*)(hbuf + (size_t)n * D);    // N f32
    int*   deg     = (int*)(dinv + n);                  // N int
    int*   off     = deg + n;                           // N int
    int*   cur     = off + n;                           // N int
    int*   srcs    = cur + n;                           // E int
    float* sdinv   = (float*)(srcs + E);                // E f32
    int*   counter = (int*)(sdinv + E);                 // 1 int
    int*   flags   = counter + 1;                       // 2 int

    probe_float_kernel<<<1, 256, 0, stream>>>(x, flags);
    probe_int_kernel<<<1, 256, 0, stream>>>(ei, flags);

    hipMemsetAsync(deg, 0, (size_t)n * sizeof(int), stream);
    hipMemsetAsync(counter, 0, sizeof(int), stream);

    degree_kernel<<<(E + 255) / 256, 256, 0, stream>>>(ei, deg, E, flags);
    dinv_kernel<<<(n + 255) / 256, 256, 0, stream>>>(deg, dinv, n);
    offsets_kernel<<<(n + 255) / 256, 256, 0, stream>>>(deg, off, cur, counter, n);
    fill_kernel<<<(E + 255) / 256, 256, 0, stream>>>(ei, dinv, cur, srcs, sdinv, E, flags);
    gemm_kernel<<<n, 64, 0, stream>>>(x, W, hbuf, flags);
    gather_kernel<<<(n + 3) / 4, 256, 0, stream>>>(hbuf, off, deg, srcs, sdinv, dinv,
                                                   b, d_out, n, flags);
}

// Round 3
// 249.428 us; speedup vs baseline: 14.8881x; 1.5724x over previous
//
#include <hip/hip_runtime.h>
#include <hip/hip_bf16.h>

#define D 128
typedef __hip_bfloat16 bf16;
typedef __hip_bfloat162 bf162;

// ================= dtype probes =================
// flags[0]: 1 if float inputs are f32, 0 if bf16
// flags[1]: 1 if edge_index is int64, 0 if int32
__global__ void probe_float_kernel(const void* __restrict__ x, int* __restrict__ flags) {
    __shared__ int cnt;
    if (threadIdx.x == 0) cnt = 0;
    __syncthreads();
    const unsigned short* u = (const unsigned short*)x;
    int bad = 0;
    for (int i = threadIdx.x; i < 2048; i += blockDim.x) {
        unsigned short v = u[2 * i];
        int e = (v >> 7) & 0xFF;
        if (e == 255 || (e != 0 && (e < 90 || e > 165))) bad++;
    }
    atomicAdd(&cnt, bad);
    __syncthreads();
    if (threadIdx.x == 0) flags[0] = (cnt > 256) ? 1 : 0;
}

__global__ void probe_int_kernel(const void* __restrict__ ei, int* __restrict__ flags) {
    __shared__ int cnt;
    if (threadIdx.x == 0) cnt = 0;
    __syncthreads();
    const int* w = (const int*)ei;
    int nz = 0;
    for (int i = threadIdx.x; i < 512; i += blockDim.x) {
        if (w[2 * i + 1] != 0) nz++;
    }
    atomicAdd(&cnt, nz);
    __syncthreads();
    if (threadIdx.x == 0) flags[1] = (cnt == 0) ? 1 : 0;
}

// ================= helpers =================
__device__ __forceinline__ int load_idx(const void* ei, long long pos, int is64) {
    if (is64) return (int)((const long long*)ei)[pos];
    return ((const int*)ei)[pos];
}

__device__ __forceinline__ float bf16bits_to_f32(unsigned short v) {
    union { unsigned u; float f; } c;
    c.u = ((unsigned)v) << 16;
    return c.f;
}

// ================= degree =================
__global__ void degree_kernel(const void* __restrict__ ei, int* __restrict__ deg,
                              int E, const int* __restrict__ flags) {
    int e = blockIdx.x * blockDim.x + threadIdx.x;
    if (e >= E) return;
    int c = load_idx(ei, (long long)E + e, flags[1]);  // col = dest
    atomicAdd(&deg[c], 1);
}

__global__ void dinv_kernel(const int* __restrict__ deg, float* __restrict__ dinv, int n) {
    int i = blockIdx.x * blockDim.x + threadIdx.x;
    if (i < n) dinv[i] = rsqrtf((float)deg[i] + 1.0f);
}

// ================= CSR offsets via per-wave scan + one atomic per wave =========
__global__ void offsets_kernel(const int* __restrict__ deg, int* __restrict__ off,
                               int* __restrict__ cur, int* __restrict__ counter, int n) {
    int i = blockIdx.x * blockDim.x + threadIdx.x;
    int lane = threadIdx.x & 63;
    int v = (i < n) ? deg[i] : 0;
    int s = v;
#pragma unroll
    for (int dlt = 1; dlt < 64; dlt <<= 1) {
        int t = __shfl_up(s, dlt, 64);
        if (lane >= dlt) s += t;
    }
    int tot = __shfl(s, 63, 64);
    int base = 0;
    if (lane == 0) base = atomicAdd(counter, tot);
    base = __shfl(base, 0, 64);
    if (i < n) {
        int o = base + s - v;  // exclusive prefix within wave
        off[i] = o;
        cur[i] = o;
    }
}

// ================= CSR fill: slot <- (src, dinv[src]) ==========================
__global__ void fill_kernel(const void* __restrict__ ei, const float* __restrict__ dinv,
                            int* __restrict__ cur, int* __restrict__ srcs,
                            float* __restrict__ sdinv, int E, const int* __restrict__ flags) {
    int e = blockIdx.x * blockDim.x + threadIdx.x;
    if (e >= E) return;
    const int i64 = flags[1];
    int s = load_idx(ei, e, i64);
    int d = load_idx(ei, (long long)E + e, i64);
    int pos = atomicAdd(&cur[d], 1);
    srcs[pos] = s;
    sdinv[pos] = dinv[s];
}

// ================= h = x @ W (bf16 out), W staged in LDS ======================
// 256 threads = 4 waves; block handles GR=32 rows. W staged in two 64-row halves.
// Thread owns 8 rows x 2 cols: wave w -> rows 8w..8w+7, lane -> cols (2l, 2l+1).
#define GR 32
#define WPAD 132  // row stride for W tile in LDS: 132*4=528B (16B-aligned, odd*4 banks shift)
__global__ void __launch_bounds__(256) gemm_kernel(
        const void* __restrict__ x, const void* __restrict__ W,
        bf16* __restrict__ hbuf, int n, const int* __restrict__ flags) {
    __shared__ float Wl[64 * WPAD];   // 33.8 KB
    __shared__ float xs[GR * D];      // 16 KB
    const int t = threadIdx.x;
    const int lane = t & 63;
    const int wave = t >> 6;
    const int r0 = blockIdx.x * GR;
    const int f = flags[0];

    // ---- stage x rows r0..r0+GR-1 into xs (zero-pad OOB rows) ----
    if (f) {
        // 32 rows * 32 float4 = 1024 float4; 4 per thread
        const float* xf = (const float*)x;
#pragma unroll
        for (int i = 0; i < 4; ++i) {
            int j = t + 256 * i;
            int row = j >> 5, c4 = j & 31;
            float4 v = make_float4(0.f, 0.f, 0.f, 0.f);
            if (r0 + row < n)
                v = *(const float4*)(xf + (size_t)(r0 + row) * D + c4 * 4);
            *(float4*)&xs[row * D + c4 * 4] = v;
        }
    } else {
        // 32 rows * 16 chunks(8 bf16) = 512; 2 per thread
        const unsigned short* xu = (const unsigned short*)x;
#pragma unroll
        for (int i = 0; i < 2; ++i) {
            int j = t + 256 * i;
            int row = j >> 4, c8 = j & 15;
            float out[8];
            if (r0 + row < n) {
                ushort4 a = *(const ushort4*)(xu + (size_t)(r0 + row) * D + c8 * 8);
                ushort4 b2 = *(const ushort4*)(xu + (size_t)(r0 + row) * D + c8 * 8 + 4);
                out[0] = bf16bits_to_f32(a.x); out[1] = bf16bits_to_f32(a.y);
                out[2] = bf16bits_to_f32(a.z); out[3] = bf16bits_to_f32(a.w);
                out[4] = bf16bits_to_f32(b2.x); out[5] = bf16bits_to_f32(b2.y);
                out[6] = bf16bits_to_f32(b2.z); out[7] = bf16bits_to_f32(b2.w);
            } else {
#pragma unroll
                for (int q = 0; q < 8; ++q) out[q] = 0.f;
            }
            *(float4*)&xs[row * D + c8 * 8] = make_float4(out[0], out[1], out[2], out[3]);
            *(float4*)&xs[row * D + c8 * 8 + 4] = make_float4(out[4], out[5], out[6], out[7]);
        }
    }

    float acc0[8], acc1[8];
#pragma unroll
    for (int rr = 0; rr < 8; ++rr) { acc0[rr] = 0.f; acc1[rr] = 0.f; }

    for (int half = 0; half < 2; ++half) {
        __syncthreads();  // xs ready (iter 0) / all waves done with prev W half
        // ---- stage W rows half*64 .. half*64+63 into Wl ----
        if (f) {
            const float* Wf = (const float*)W + (size_t)half * 64 * D;
#pragma unroll
            for (int i = 0; i < 8; ++i) {
                int j = t + 256 * i;
                int row = j >> 5, c4 = j & 31;
                *(float4*)&Wl[row * WPAD + c4 * 4] =
                    *(const float4*)(Wf + (size_t)row * D + c4 * 4);
            }
        } else {
            const unsigned short* Wu = (const unsigned short*)W + (size_t)half * 64 * D;
#pragma unroll
            for (int i = 0; i < 4; ++i) {
                int j = t + 256 * i;
                int row = j >> 4, c8 = j & 15;
                ushort4 a = *(const ushort4*)(Wu + (size_t)row * D + c8 * 8);
                ushort4 b2 = *(const ushort4*)(Wu + (size_t)row * D + c8 * 8 + 4);
                *(float4*)&Wl[row * WPAD + c8 * 8] = make_float4(
                    bf16bits_to_f32(a.x), bf16bits_to_f32(a.y),
                    bf16bits_to_f32(a.z), bf16bits_to_f32(a.w));
                *(float4*)&Wl[row * WPAD + c8 * 8 + 4] = make_float4(
                    bf16bits_to_f32(b2.x), bf16bits_to_f32(b2.y),
                    bf16bits_to_f32(b2.z), bf16bits_to_f32(b2.w));
            }
        }
        __syncthreads();

        // ---- compute k = half*64 .. half*64+63 ----
#pragma unroll 4
        for (int kc = 0; kc < 16; ++kc) {
            float4 xv[8];
#pragma unroll
            for (int rr = 0; rr < 8; ++rr)
                xv[rr] = *(const float4*)&xs[(wave * 8 + rr) * D + half * 64 + kc * 4];
#pragma unroll
            for (int kk = 0; kk < 4; ++kk) {
                float2 wv = *(const float2*)&Wl[(kc * 4 + kk) * WPAD + 2 * lane];
#pragma unroll
                for (int rr = 0; rr < 8; ++rr) {
                    float xk = (kk == 0) ? xv[rr].x : (kk == 1) ? xv[rr].y
                             : (kk == 2) ? xv[rr].z : xv[rr].w;
                    acc0[rr] += xk * wv.x;
                    acc1[rr] += xk * wv.y;
                }
            }
        }
    }

    // ---- store h rows as bf16 ----
    bf162* hp = (bf162*)hbuf;
#pragma unroll
    for (int rr = 0; rr < 8; ++rr) {
        int gr = r0 + wave * 8 + rr;
        if (gr < n) {
            bf162 o;
            o.x = __float2bfloat16(acc0[rr]);
            o.y = __float2bfloat16(acc1[rr]);
            hp[(size_t)gr * 64 + lane] = o;
        }
    }
}

// ================= gather: out[d] = sum_in norm*h[s] + dinv^2*h[d] + b =========
// One wave per destination; lane owns columns (2*lane, 2*lane+1).
__global__ void gather_kernel(const bf16* __restrict__ hbuf, const int* __restrict__ off,
                              const int* __restrict__ deg, const int* __restrict__ srcs,
                              const float* __restrict__ sdinv, const float* __restrict__ dinv,
                              const void* __restrict__ b, void* __restrict__ out,
                              int n, const int* __restrict__ flags) {
    int wave = threadIdx.x >> 6;              // 0..3
    int lane = threadIdx.x & 63;
    int d = blockIdx.x * 4 + wave;
    if (d >= n) return;

    const bf162* h2 = (const bf162*)hbuf;
    float dd = dinv[d];
    int start = off[d];
    int len = deg[d];

    float a0 = 0.f, a1 = 0.f;
    for (int base = 0; base < len; base += 64) {
        int m = len - base; if (m > 64) m = 64;
        int sreg = 0; float nreg = 0.f;
        if (lane < m) {
            sreg = srcs[start + base + lane];
            nreg = sdinv[start + base + lane];
        }
        for (int k = 0; k < m; ++k) {
            int s = __shfl(sreg, k, 64);
            float nd = __shfl(nreg, k, 64) * dd;
            bf162 hv = h2[(size_t)s * 64 + lane];
            a0 += nd * __bfloat162float(hv.x);
            a1 += nd * __bfloat162float(hv.y);
        }
    }
    // self loop
    bf162 hs = h2[(size_t)d * 64 + lane];
    float dd2 = dd * dd;
    a0 += dd2 * __bfloat162float(hs.x);
    a1 += dd2 * __bfloat162float(hs.y);

    if (flags[0]) {
        float2 bb = ((const float2*)b)[lane];
        float2 o; o.x = a0 + bb.x; o.y = a1 + bb.y;
        ((float2*)out)[(size_t)d * 64 + lane] = o;
    } else {
        bf162 bb = ((const bf162*)b)[lane];
        bf162 o;
        o.x = __float2bfloat16(a0 + __bfloat162float(bb.x));
        o.y = __float2bfloat16(a1 + __bfloat162float(bb.y));
        ((bf162*)out)[(size_t)d * 64 + lane] = o;
    }
}

extern "C" void kernel_launch(void* const* d_in, const int* in_sizes, int n_in,
                              void* d_out, int out_size, void* d_ws, size_t ws_size,
                              hipStream_t stream) {
    const void* x = d_in[0];
    const void* ei = d_in[1];
    const void* W = d_in[2];
    const void* b = d_in[3];

    const int n = in_sizes[0] / D;   // 50000
    const int E = in_sizes[1] / 2;   // 600000

    // ws layout
    bf16*  hbuf    = (bf16*)d_ws;                       // N*D bf16 = 12.8MB
    float* dinv    = (float*)(hbuf + (size_t)n * D);    // N f32
    int*   deg     = (int*)(dinv + n);                  // N int
    int*   off     = deg + n;                           // N int
    int*   cur     = off + n;                           // N int
    int*   srcs    = cur + n;                           // E int
    float* sdinv   = (float*)(srcs + E);                // E f32
    int*   counter = (int*)(sdinv + E);                 // 1 int
    int*   flags   = counter + 1;                       // 2 int

    probe_float_kernel<<<1, 256, 0, stream>>>(x, flags);
    probe_int_kernel<<<1, 256, 0, stream>>>(ei, flags);

    hipMemsetAsync(deg, 0, (size_t)n * sizeof(int), stream);
    hipMemsetAsync(counter, 0, sizeof(int), stream);

    degree_kernel<<<(E + 255) / 256, 256, 0, stream>>>(ei, deg, E, flags);
    dinv_kernel<<<(n + 255) / 256, 256, 0, stream>>>(deg, dinv, n);
    offsets_kernel<<<(n + 255) / 256, 256, 0, stream>>>(deg, off, cur, counter, n);
    fill_kernel<<<(E + 255) / 256, 256, 0, stream>>>(ei, dinv, cur, srcs, sdinv, E, flags);
    gemm_kernel<<<(n + GR - 1) / GR, 256, 0, stream>>>(x, W, hbuf, n, flags);
    gather_kernel<<<(n + 3) / 4, 256, 0, stream>>>(hbuf, off, deg, srcs, sdinv, dinv,
                                                   b, d_out, n, flags);
}

// Round 4
// 208.348 us; speedup vs baseline: 17.8235x; 1.1972x over previous
//
#include <hip/hip_runtime.h>
#include <hip/hip_bf16.h>

#define D 128
#define GR 32
#define WPAD 132
typedef __hip_bfloat16 bf16;
typedef __hip_bfloat162 bf162;

// ================= helpers =================
__device__ __forceinline__ int load_idx(const void* ei, long long pos, int is64) {
    if (is64) return (int)((const long long*)ei)[pos];
    return ((const int*)ei)[pos];
}

__device__ __forceinline__ float bf16bits_to_f32(unsigned short v) {
    union { unsigned u; float f; } c;
    c.u = ((unsigned)v) << 16;
    return c.f;
}

// ================= init: zero deg/counter + dtype probes ======================
// flags[0]: 1 if float inputs are f32, 0 if bf16
// flags[1]: 1 if edge_index is int64, 0 if int32
__global__ void init_kernel(const void* __restrict__ x, const void* __restrict__ ei,
                            int* __restrict__ deg, int* __restrict__ counter,
                            int* __restrict__ flags, int n) {
    int i = blockIdx.x * blockDim.x + threadIdx.x;
    if (i < n) deg[i] = 0;
    if (i == 0) *counter = 0;

    if (blockIdx.x == 0) {
        // float probe: low 16 bits of each 32-bit word are valid-bf16-exponent iff bf16 data
        __shared__ int cnt;
        if (threadIdx.x == 0) cnt = 0;
        __syncthreads();
        const unsigned short* u = (const unsigned short*)x;
        int bad = 0;
        for (int j = threadIdx.x; j < 2048; j += blockDim.x) {
            unsigned short v = u[2 * j];
            int e = (v >> 7) & 0xFF;
            if (e == 255 || (e != 0 && (e < 90 || e > 165))) bad++;
        }
        atomicAdd(&cnt, bad);
        __syncthreads();
        if (threadIdx.x == 0) flags[0] = (cnt > 256) ? 1 : 0;
    } else if (blockIdx.x == 1) {
        // int probe: odd 32-bit words all zero iff int64 (values < 2^31, nonneg)
        __shared__ int cnt;
        if (threadIdx.x == 0) cnt = 0;
        __syncthreads();
        const int* w = (const int*)ei;
        int nz = 0;
        for (int j = threadIdx.x; j < 512; j += blockDim.x) {
            if (w[2 * j + 1] != 0) nz++;
        }
        atomicAdd(&cnt, nz);
        __syncthreads();
        if (threadIdx.x == 0) flags[1] = (cnt == 0) ? 1 : 0;
    }
}

// ================= fused: degree (atomic-bound) ∥ gemm (compute-bound) =========
// blocks [0, ngemm): h = x @ W tile; blocks [ngemm, ...): degree atomics.
// The two are data-independent; fusing overlaps them instead of serializing.
__global__ void __launch_bounds__(256) degree_gemm_kernel(
        const void* __restrict__ ei, int* __restrict__ deg, int E,
        const void* __restrict__ x, const void* __restrict__ W,
        bf16* __restrict__ hbuf, int n, int ngemm, const int* __restrict__ flags) {
    __shared__ float Wl[64 * WPAD];   // 33.8 KB
    __shared__ float xs[GR * D];      // 16 KB

    if (blockIdx.x >= ngemm) {
        // ---------------- degree ----------------
        int e = (blockIdx.x - ngemm) * blockDim.x + threadIdx.x;
        if (e < E) {
            int c = load_idx(ei, (long long)E + e, flags[1]);  // col = dest
            atomicAdd(&deg[c], 1);
        }
        return;
    }

    // ---------------- gemm tile: 32 rows, thread owns 8 rows x 2 cols ----------
    const int t = threadIdx.x;
    const int lane = t & 63;
    const int wave = t >> 6;
    const int r0 = blockIdx.x * GR;
    const int f = flags[0];

    if (f) {
        const float* xf = (const float*)x;
#pragma unroll
        for (int i = 0; i < 4; ++i) {
            int j = t + 256 * i;
            int row = j >> 5, c4 = j & 31;
            float4 v = make_float4(0.f, 0.f, 0.f, 0.f);
            if (r0 + row < n)
                v = *(const float4*)(xf + (size_t)(r0 + row) * D + c4 * 4);
            *(float4*)&xs[row * D + c4 * 4] = v;
        }
    } else {
        const unsigned short* xu = (const unsigned short*)x;
#pragma unroll
        for (int i = 0; i < 2; ++i) {
            int j = t + 256 * i;
            int row = j >> 4, c8 = j & 15;
            float out[8];
            if (r0 + row < n) {
                ushort4 a = *(const ushort4*)(xu + (size_t)(r0 + row) * D + c8 * 8);
                ushort4 b2 = *(const ushort4*)(xu + (size_t)(r0 + row) * D + c8 * 8 + 4);
                out[0] = bf16bits_to_f32(a.x); out[1] = bf16bits_to_f32(a.y);
                out[2] = bf16bits_to_f32(a.z); out[3] = bf16bits_to_f32(a.w);
                out[4] = bf16bits_to_f32(b2.x); out[5] = bf16bits_to_f32(b2.y);
                out[6] = bf16bits_to_f32(b2.z); out[7] = bf16bits_to_f32(b2.w);
            } else {
#pragma unroll
                for (int q = 0; q < 8; ++q) out[q] = 0.f;
            }
            *(float4*)&xs[row * D + c8 * 8] = make_float4(out[0], out[1], out[2], out[3]);
            *(float4*)&xs[row * D + c8 * 8 + 4] = make_float4(out[4], out[5], out[6], out[7]);
        }
    }

    float acc0[8], acc1[8];
#pragma unroll
    for (int rr = 0; rr < 8; ++rr) { acc0[rr] = 0.f; acc1[rr] = 0.f; }

    for (int half = 0; half < 2; ++half) {
        __syncthreads();
        if (f) {
            const float* Wf = (const float*)W + (size_t)half * 64 * D;
#pragma unroll
            for (int i = 0; i < 8; ++i) {
                int j = t + 256 * i;
                int row = j >> 5, c4 = j & 31;
                *(float4*)&Wl[row * WPAD + c4 * 4] =
                    *(const float4*)(Wf + (size_t)row * D + c4 * 4);
            }
        } else {
            const unsigned short* Wu = (const unsigned short*)W + (size_t)half * 64 * D;
#pragma unroll
            for (int i = 0; i < 4; ++i) {
                int j = t + 256 * i;
                int row = j >> 4, c8 = j & 15;
                ushort4 a = *(const ushort4*)(Wu + (size_t)row * D + c8 * 8);
                ushort4 b2 = *(const ushort4*)(Wu + (size_t)row * D + c8 * 8 + 4);
                *(float4*)&Wl[row * WPAD + c8 * 8] = make_float4(
                    bf16bits_to_f32(a.x), bf16bits_to_f32(a.y),
                    bf16bits_to_f32(a.z), bf16bits_to_f32(a.w));
                *(float4*)&Wl[row * WPAD + c8 * 8 + 4] = make_float4(
                    bf16bits_to_f32(b2.x), bf16bits_to_f32(b2.y),
                    bf16bits_to_f32(b2.z), bf16bits_to_f32(b2.w));
            }
        }
        __syncthreads();

#pragma unroll 4
        for (int kc = 0; kc < 16; ++kc) {
            float4 xv[8];
#pragma unroll
            for (int rr = 0; rr < 8; ++rr)
                xv[rr] = *(const float4*)&xs[(wave * 8 + rr) * D + half * 64 + kc * 4];
#pragma unroll
            for (int kk = 0; kk < 4; ++kk) {
                float2 wv = *(const float2*)&Wl[(kc * 4 + kk) * WPAD + 2 * lane];
#pragma unroll
                for (int rr = 0; rr < 8; ++rr) {
                    float xk = (kk == 0) ? xv[rr].x : (kk == 1) ? xv[rr].y
                             : (kk == 2) ? xv[rr].z : xv[rr].w;
                    acc0[rr] += xk * wv.x;
                    acc1[rr] += xk * wv.y;
                }
            }
        }
    }

    bf162* hp = (bf162*)hbuf;
#pragma unroll
    for (int rr = 0; rr < 8; ++rr) {
        int gr = r0 + wave * 8 + rr;
        if (gr < n) {
            bf162 o;
            o.x = __float2bfloat16(acc0[rr]);
            o.y = __float2bfloat16(acc1[rr]);
            hp[(size_t)gr * 64 + lane] = o;
        }
    }
}

// ================= scan: dinv + CSR offsets (wave scan, 1 atomic/wave) =========
__global__ void scan_kernel(const int* __restrict__ deg, float* __restrict__ dinv,
                            int* __restrict__ off, int* __restrict__ cur,
                            int* __restrict__ counter, int n) {
    int i = blockIdx.x * blockDim.x + threadIdx.x;
    int lane = threadIdx.x & 63;
    int v = (i < n) ? deg[i] : 0;
    if (i < n) dinv[i] = rsqrtf((float)v + 1.0f);
    int s = v;
#pragma unroll
    for (int dlt = 1; dlt < 64; dlt <<= 1) {
        int t = __shfl_up(s, dlt, 64);
        if (lane >= dlt) s += t;
    }
    int tot = __shfl(s, 63, 64);
    int base = 0;
    if (lane == 0) base = atomicAdd(counter, tot);
    base = __shfl(base, 0, 64);
    if (i < n) {
        int o = base + s - v;  // exclusive prefix within wave
        off[i] = o;
        cur[i] = o;
    }
}

// ================= fill: slab[pos] = {src, bits(dinv[src])} (one 8B store) =====
__global__ void fill_kernel(const void* __restrict__ ei, const float* __restrict__ dinv,
                            int* __restrict__ cur, int2* __restrict__ slab,
                            int E, const int* __restrict__ flags) {
    int e = blockIdx.x * blockDim.x + threadIdx.x;
    if (e >= E) return;
    const int i64 = flags[1];
    int s = load_idx(ei, e, i64);
    int d = load_idx(ei, (long long)E + e, i64);
    int pos = atomicAdd(&cur[d], 1);
    slab[pos] = make_int2(s, __float_as_int(dinv[s]));
}

// ================= gather: out[d] = sum_in norm*h[s] + dinv^2*h[d] + b =========
// One wave per destination; lane owns columns (2*lane, 2*lane+1).
// Edge loop hand-pipelined 4-deep: 4 coalesced 512B h-row loads in flight.
__global__ void gather_kernel(const bf16* __restrict__ hbuf, const int* __restrict__ off,
                              const int* __restrict__ deg, const int2* __restrict__ slab,
                              const float* __restrict__ dinv, const void* __restrict__ b,
                              void* __restrict__ out, int n, const int* __restrict__ flags) {
    int wave = threadIdx.x >> 6;              // 0..3
    int lane = threadIdx.x & 63;
    int d = blockIdx.x * 4 + wave;
    if (d >= n) return;

    const bf162* h2 = (const bf162*)hbuf;
    float dd = dinv[d];
    int start = off[d];
    int len = deg[d];

    float a0 = 0.f, a1 = 0.f;
    for (int base = 0; base < len; base += 64) {
        int m = len - base; if (m > 64) m = 64;
        int2 rec = make_int2(0, 0);
        if (lane < m) rec = slab[start + base + lane];

        int k = 0;
        for (; k + 4 <= m; k += 4) {
            int s0 = __shfl(rec.x, k, 64);
            int s1 = __shfl(rec.x, k + 1, 64);
            int s2 = __shfl(rec.x, k + 2, 64);
            int s3 = __shfl(rec.x, k + 3, 64);
            float n0 = __int_as_float(__shfl(rec.y, k, 64)) * dd;
            float n1 = __int_as_float(__shfl(rec.y, k + 1, 64)) * dd;
            float n2 = __int_as_float(__shfl(rec.y, k + 2, 64)) * dd;
            float n3 = __int_as_float(__shfl(rec.y, k + 3, 64)) * dd;
            bf162 h0 = h2[(size_t)s0 * 64 + lane];
            bf162 h1 = h2[(size_t)s1 * 64 + lane];
            bf162 hv2 = h2[(size_t)s2 * 64 + lane];
            bf162 hv3 = h2[(size_t)s3 * 64 + lane];
            a0 += n0 * __bfloat162float(h0.x);  a1 += n0 * __bfloat162float(h0.y);
            a0 += n1 * __bfloat162float(h1.x);  a1 += n1 * __bfloat162float(h1.y);
            a0 += n2 * __bfloat162float(hv2.x); a1 += n2 * __bfloat162float(hv2.y);
            a0 += n3 * __bfloat162float(hv3.x); a1 += n3 * __bfloat162float(hv3.y);
        }
        for (; k < m; ++k) {
            int s = __shfl(rec.x, k, 64);
            float nd = __int_as_float(__shfl(rec.y, k, 64)) * dd;
            bf162 hv = h2[(size_t)s * 64 + lane];
            a0 += nd * __bfloat162float(hv.x);
            a1 += nd * __bfloat162float(hv.y);
        }
    }
    // self loop
    bf162 hs = h2[(size_t)d * 64 + lane];
    float dd2 = dd * dd;
    a0 += dd2 * __bfloat162float(hs.x);
    a1 += dd2 * __bfloat162float(hs.y);

    if (flags[0]) {
        float2 bb = ((const float2*)b)[lane];
        float2 o; o.x = a0 + bb.x; o.y = a1 + bb.y;
        ((float2*)out)[(size_t)d * 64 + lane] = o;
    } else {
        bf162 bb = ((const bf162*)b)[lane];
        bf162 o;
        o.x = __float2bfloat16(a0 + __bfloat162float(bb.x));
        o.y = __float2bfloat16(a1 + __bfloat162float(bb.y));
        ((bf162*)out)[(size_t)d * 64 + lane] = o;
    }
}

extern "C" void kernel_launch(void* const* d_in, const int* in_sizes, int n_in,
                              void* d_out, int out_size, void* d_ws, size_t ws_size,
                              hipStream_t stream) {
    const void* x = d_in[0];
    const void* ei = d_in[1];
    const void* W = d_in[2];
    const void* b = d_in[3];

    const int n = in_sizes[0] / D;   // 50000
    const int E = in_sizes[1] / 2;   // 600000

    // ws layout (all segments 8B-aligned)
    bf16*  hbuf    = (bf16*)d_ws;                       // N*D bf16 = 12.8MB
    float* dinv    = (float*)(hbuf + (size_t)n * D);    // N f32
    int*   deg     = (int*)(dinv + n);                  // N int
    int*   off     = deg + n;                           // N int
    int*   cur     = off + n;                           // N int
    int2*  slab    = (int2*)(cur + n);                  // E int2 = 4.8MB
    int*   counter = (int*)(slab + E);                  // 1 int
    int*   flags   = counter + 1;                       // 2 int

    const int ngemm = (n + GR - 1) / GR;
    const int ndeg  = (E + 255) / 256;

    init_kernel<<<(n + 255) / 256, 256, 0, stream>>>(x, ei, deg, counter, flags, n);
    degree_gemm_kernel<<<ngemm + ndeg, 256, 0, stream>>>(ei, deg, E, x, W, hbuf, n,
                                                         ngemm, flags);
    scan_kernel<<<(n + 255) / 256, 256, 0, stream>>>(deg, dinv, off, cur, counter, n);
    fill_kernel<<<(E + 255) / 256, 256, 0, stream>>>(ei, dinv, cur, slab, E, flags);
    gather_kernel<<<(n + 3) / 4, 256, 0, stream>>>(hbuf, off, deg, slab, dinv,
                                                   b, d_out, n, flags);
}

// Round 5
// 193.394 us; speedup vs baseline: 19.2018x; 1.0773x over previous
//
#include <hip/hip_runtime.h>
#include <hip/hip_bf16.h>

#define D 128
typedef __hip_bfloat16 bf16;
typedef __hip_bfloat162 bf162;
typedef __attribute__((ext_vector_type(8))) short bf16x8;
typedef __attribute__((ext_vector_type(4))) float f32x4;

// ================= helpers =================
__device__ __forceinline__ int load_idx(const void* ei, long long pos, int is64) {
    if (is64) return (int)((const long long*)ei)[pos];
    return ((const int*)ei)[pos];
}

__device__ __forceinline__ float bf16bits_to_f32(unsigned short v) {
    union { unsigned u; float f; } c;
    c.u = ((unsigned)v) << 16;
    return c.f;
}

__device__ __forceinline__ unsigned short f32_to_bf16bits(float v) {
    bf16 b = __float2bfloat16(v);  // RNE
    return *reinterpret_cast<unsigned short*>(&b);
}

// ================= init: zero deg/counter + dtype probes ======================
// flags[0]: 1 if float inputs are f32, 0 if bf16
// flags[1]: 1 if edge_index is int64, 0 if int32
__global__ void init_kernel(const void* __restrict__ x, const void* __restrict__ ei,
                            int* __restrict__ deg, int* __restrict__ counter,
                            int* __restrict__ flags, int n) {
    int i = blockIdx.x * blockDim.x + threadIdx.x;
    if (i < n) deg[i] = 0;
    if (i == 0) *counter = 0;

    if (blockIdx.x == 0) {
        __shared__ int cnt;
        if (threadIdx.x == 0) cnt = 0;
        __syncthreads();
        const unsigned short* u = (const unsigned short*)x;
        int bad = 0;
        for (int j = threadIdx.x; j < 2048; j += blockDim.x) {
            unsigned short v = u[2 * j];
            int e = (v >> 7) & 0xFF;
            if (e == 255 || (e != 0 && (e < 90 || e > 165))) bad++;
        }
        atomicAdd(&cnt, bad);
        __syncthreads();
        if (threadIdx.x == 0) flags[0] = (cnt > 256) ? 1 : 0;
    } else if (blockIdx.x == 1) {
        __shared__ int cnt;
        if (threadIdx.x == 0) cnt = 0;
        __syncthreads();
        const int* w = (const int*)ei;
        int nz = 0;
        for (int j = threadIdx.x; j < 512; j += blockDim.x) {
            if (w[2 * j + 1] != 0) nz++;
        }
        atomicAdd(&cnt, nz);
        __syncthreads();
        if (threadIdx.x == 0) flags[1] = (cnt == 0) ? 1 : 0;
    }
}

// ================= fused: degree (atomic-bound) ∥ MFMA gemm ====================
// blocks [0, ngemm): h = x @ W via mfma_f32_16x16x32_bf16 with hi/lo split
// blocks [ngemm, ...): degree atomics. Data-independent -> overlap.
//
// Fragment conventions (slot = (g = lane>>4, i = vector elem 0..7)):
//   A: lane holds row (lane&15), k = 32*kt + 8*g + i
//   B: lane holds col (lane&15), k = 32*kt + 8*g + i   (same slot map -> any HW
//      k-permutation cancels between A and B loaders)
//   C/D (HW-verified m89/m91): col = lane&15, row = 4*(lane>>4) + reg
__global__ void __launch_bounds__(256) degree_gemm_kernel(
        const void* __restrict__ ei, int* __restrict__ deg, int E,
        const void* __restrict__ x, const void* __restrict__ W,
        bf16* __restrict__ hbuf, int n, int ngemm, const int* __restrict__ flags) {
    extern __shared__ unsigned short Wfrag[];  // 64KB: hi frags [0,2048), lo [2048,4096) chunks

    if (blockIdx.x >= ngemm) {
        int e = (blockIdx.x - ngemm) * blockDim.x + threadIdx.x;
        if (e < E) {
            int c = load_idx(ei, (long long)E + e, flags[1]);  // col = dest
            atomicAdd(&deg[c], 1);
        }
        return;
    }

    const int t = threadIdx.x;
    const int lane = t & 63;
    const int wave = t >> 6;
    const int g = lane >> 4;     // k-group 0..3
    const int rl = lane & 15;    // A-row / B-col within tile
    const int r0 = blockIdx.x * 64;
    const int f = flags[0];

    // ---- A fragments: row r0 + 16*wave + rl, all 4 k-steps, hi/lo split ----
    bf16x8 ah[4], al[4];
    const int arow = r0 + wave * 16 + rl;
    if (f) {
        const float* xr = (const float*)x + (size_t)arow * D;
#pragma unroll
        for (int kt = 0; kt < 4; ++kt) {
            float u[8];
            if (arow < n) {
                float4 u0 = *(const float4*)(xr + kt * 32 + g * 8);
                float4 u1 = *(const float4*)(xr + kt * 32 + g * 8 + 4);
                u[0] = u0.x; u[1] = u0.y; u[2] = u0.z; u[3] = u0.w;
                u[4] = u1.x; u[5] = u1.y; u[6] = u1.z; u[7] = u1.w;
            } else {
#pragma unroll
                for (int i = 0; i < 8; ++i) u[i] = 0.f;
            }
#pragma unroll
            for (int i = 0; i < 8; ++i) {
                unsigned short hb = f32_to_bf16bits(u[i]);
                ah[kt][i] = (short)hb;
                al[kt][i] = (short)f32_to_bf16bits(u[i] - bf16bits_to_f32(hb));
            }
        }
    } else {
        const unsigned short* xr = (const unsigned short*)x + (size_t)arow * D;
#pragma unroll
        for (int kt = 0; kt < 4; ++kt) {
            bf16x8 v = {};
            if (arow < n) v = *(const bf16x8*)(xr + kt * 32 + g * 8);
            ah[kt] = v;
            al[kt] = v;  // unused on bf16 path
        }
    }

    // ---- stage W fragments into LDS (once per block) ----
    // chunk cid = (ct*4 + kt)*64 + lane' ; contents: W[32*kt+8*g'+i][16*ct+rl']
    if (f) {
        const float* Wf = (const float*)W;
#pragma unroll
        for (int c8 = 0; c8 < 8; ++c8) {
            int cid = t + 256 * c8;
            int l2 = cid & 63, ktct = cid >> 6;
            int kb = (ktct & 3) * 32 + (l2 >> 4) * 8;
            int cc = (ktct >> 2) * 16 + (l2 & 15);
            bf16x8 hi, lo;
#pragma unroll
            for (int i = 0; i < 8; ++i) {
                float wv = Wf[(size_t)(kb + i) * D + cc];
                unsigned short hb = f32_to_bf16bits(wv);
                hi[i] = (short)hb;
                lo[i] = (short)f32_to_bf16bits(wv - bf16bits_to_f32(hb));
            }
            *(bf16x8*)&Wfrag[(size_t)cid * 8] = hi;
            *(bf16x8*)&Wfrag[(size_t)(2048 + cid) * 8] = lo;
        }
    } else {
        const unsigned short* Wu = (const unsigned short*)W;
#pragma unroll
        for (int c8 = 0; c8 < 8; ++c8) {
            int cid = t + 256 * c8;
            int l2 = cid & 63, ktct = cid >> 6;
            int kb = (ktct & 3) * 32 + (l2 >> 4) * 8;
            int cc = (ktct >> 2) * 16 + (l2 & 15);
            bf16x8 hi;
#pragma unroll
            for (int i = 0; i < 8; ++i)
                hi[i] = (short)Wu[(size_t)(kb + i) * D + cc];
            *(bf16x8*)&Wfrag[(size_t)cid * 8] = hi;
        }
    }
    __syncthreads();

    // ---- MFMA main loop: col-tile pairs ----
#pragma unroll
    for (int cp = 0; cp < 4; ++cp) {
        const int ct0 = cp * 2, ct1 = cp * 2 + 1;
        f32x4 acc0 = {0.f, 0.f, 0.f, 0.f};
        f32x4 acc1 = {0.f, 0.f, 0.f, 0.f};
#pragma unroll
        for (int kt = 0; kt < 4; ++kt) {
            int cid0 = (ct0 * 4 + kt) * 64 + lane;
            int cid1 = (ct1 * 4 + kt) * 64 + lane;
            bf16x8 bh0 = *(const bf16x8*)&Wfrag[(size_t)cid0 * 8];
            bf16x8 bh1 = *(const bf16x8*)&Wfrag[(size_t)cid1 * 8];
            acc0 = __builtin_amdgcn_mfma_f32_16x16x32_bf16(ah[kt], bh0, acc0, 0, 0, 0);
            acc1 = __builtin_amdgcn_mfma_f32_16x16x32_bf16(ah[kt], bh1, acc1, 0, 0, 0);
            if (f) {
                bf16x8 bl0 = *(const bf16x8*)&Wfrag[(size_t)(2048 + cid0) * 8];
                bf16x8 bl1 = *(const bf16x8*)&Wfrag[(size_t)(2048 + cid1) * 8];
                acc0 = __builtin_amdgcn_mfma_f32_16x16x32_bf16(ah[kt], bl0, acc0, 0, 0, 0);
                acc1 = __builtin_amdgcn_mfma_f32_16x16x32_bf16(ah[kt], bl1, acc1, 0, 0, 0);
                acc0 = __builtin_amdgcn_mfma_f32_16x16x32_bf16(al[kt], bh0, acc0, 0, 0, 0);
                acc1 = __builtin_amdgcn_mfma_f32_16x16x32_bf16(al[kt], bh1, acc1, 0, 0, 0);
            }
        }
#pragma unroll
        for (int reg = 0; reg < 4; ++reg) {
            int r = r0 + wave * 16 + g * 4 + reg;
            if (r < n) {
                hbuf[(size_t)r * D + ct0 * 16 + rl] = __float2bfloat16(acc0[reg]);
                hbuf[(size_t)r * D + ct1 * 16 + rl] = __float2bfloat16(acc1[reg]);
            }
        }
    }
}

// ================= scan: dinv + CSR offsets (wave scan, 1 atomic/wave) =========
__global__ void scan_kernel(const int* __restrict__ deg, float* __restrict__ dinv,
                            int* __restrict__ off, int* __restrict__ cur,
                            int* __restrict__ counter, int n) {
    int i = blockIdx.x * blockDim.x + threadIdx.x;
    int lane = threadIdx.x & 63;
    int v = (i < n) ? deg[i] : 0;
    if (i < n) dinv[i] = rsqrtf((float)v + 1.0f);
    int s = v;
#pragma unroll
    for (int dlt = 1; dlt < 64; dlt <<= 1) {
        int t = __shfl_up(s, dlt, 64);
        if (lane >= dlt) s += t;
    }
    int tot = __shfl(s, 63, 64);
    int base = 0;
    if (lane == 0) base = atomicAdd(counter, tot);
    base = __shfl(base, 0, 64);
    if (i < n) {
        int o = base + s - v;  // exclusive prefix within wave
        off[i] = o;
        cur[i] = o;
    }
}

// ================= fill: slab[pos] = {src, bits(dinv[src])} (one 8B store) =====
__global__ void fill_kernel(const void* __restrict__ ei, const float* __restrict__ dinv,
                            int* __restrict__ cur, int2* __restrict__ slab,
                            int E, const int* __restrict__ flags) {
    int e = blockIdx.x * blockDim.x + threadIdx.x;
    if (e >= E) return;
    const int i64 = flags[1];
    int s = load_idx(ei, e, i64);
    int d = load_idx(ei, (long long)E + e, i64);
    int pos = atomicAdd(&cur[d], 1);
    slab[pos] = make_int2(s, __float_as_int(dinv[s]));
}

// ================= gather: out[d] = sum_in norm*h[s] + dinv^2*h[d] + b =========
__global__ void gather_kernel(const bf16* __restrict__ hbuf, const int* __restrict__ off,
                              const int* __restrict__ deg, const int2* __restrict__ slab,
                              const float* __restrict__ dinv, const void* __restrict__ b,
                              void* __restrict__ out, int n, const int* __restrict__ flags) {
    int wave = threadIdx.x >> 6;              // 0..3
    int lane = threadIdx.x & 63;
    int d = blockIdx.x * 4 + wave;
    if (d >= n) return;

    const bf162* h2 = (const bf162*)hbuf;
    float dd = dinv[d];
    int start = off[d];
    int len = deg[d];

    float a0 = 0.f, a1 = 0.f;
    for (int base = 0; base < len; base += 64) {
        int m = len - base; if (m > 64) m = 64;
        int2 rec = make_int2(0, 0);
        if (lane < m) rec = slab[start + base + lane];

        int k = 0;
        for (; k + 4 <= m; k += 4) {
            int s0 = __shfl(rec.x, k, 64);
            int s1 = __shfl(rec.x, k + 1, 64);
            int s2 = __shfl(rec.x, k + 2, 64);
            int s3 = __shfl(rec.x, k + 3, 64);
            float n0 = __int_as_float(__shfl(rec.y, k, 64)) * dd;
            float n1 = __int_as_float(__shfl(rec.y, k + 1, 64)) * dd;
            float n2 = __int_as_float(__shfl(rec.y, k + 2, 64)) * dd;
            float n3 = __int_as_float(__shfl(rec.y, k + 3, 64)) * dd;
            bf162 h0 = h2[(size_t)s0 * 64 + lane];
            bf162 h1 = h2[(size_t)s1 * 64 + lane];
            bf162 hv2 = h2[(size_t)s2 * 64 + lane];
            bf162 hv3 = h2[(size_t)s3 * 64 + lane];
            a0 += n0 * __bfloat162float(h0.x);  a1 += n0 * __bfloat162float(h0.y);
            a0 += n1 * __bfloat162float(h1.x);  a1 += n1 * __bfloat162float(h1.y);
            a0 += n2 * __bfloat162float(hv2.x); a1 += n2 * __bfloat162float(hv2.y);
            a0 += n3 * __bfloat162float(hv3.x); a1 += n3 * __bfloat162float(hv3.y);
        }
        for (; k < m; ++k) {
            int s = __shfl(rec.x, k, 64);
            float nd = __int_as_float(__shfl(rec.y, k, 64)) * dd;
            bf162 hv = h2[(size_t)s * 64 + lane];
            a0 += nd * __bfloat162float(hv.x);
            a1 += nd * __bfloat162float(hv.y);
        }
    }
    // self loop
    bf162 hs = h2[(size_t)d * 64 + lane];
    float dd2 = dd * dd;
    a0 += dd2 * __bfloat162float(hs.x);
    a1 += dd2 * __bfloat162float(hs.y);

    if (flags[0]) {
        float2 bb = ((const float2*)b)[lane];
        float2 o; o.x = a0 + bb.x; o.y = a1 + bb.y;
        ((float2*)out)[(size_t)d * 64 + lane] = o;
    } else {
        bf162 bb = ((const bf162*)b)[lane];
        bf162 o;
        o.x = __float2bfloat16(a0 + __bfloat162float(bb.x));
        o.y = __float2bfloat16(a1 + __bfloat162float(bb.y));
        ((bf162*)out)[(size_t)d * 64 + lane] = o;
    }
}

extern "C" void kernel_launch(void* const* d_in, const int* in_sizes, int n_in,
                              void* d_out, int out_size, void* d_ws, size_t ws_size,
                              hipStream_t stream) {
    const void* x = d_in[0];
    const void* ei = d_in[1];
    const void* W = d_in[2];
    const void* b = d_in[3];

    const int n = in_sizes[0] / D;   // 50000 (element counts)
    const int E = in_sizes[1] / 2;   // 600000

    // ws layout (all segments 8B-aligned)
    bf16*  hbuf    = (bf16*)d_ws;                       // N*D bf16 = 12.8MB
    float* dinv    = (float*)(hbuf + (size_t)n * D);    // N f32
    int*   deg     = (int*)(dinv + n);                  // N int
    int*   off     = deg + n;                           // N int
    int*   cur     = off + n;                           // N int
    int2*  slab    = (int2*)(cur + n);                  // E int2 = 4.8MB
    int*   counter = (int*)(slab + E);                  // 1 int
    int*   flags   = counter + 1;                       // 2 int

    const int ngemm = (n + 63) / 64;
    const int ndeg  = (E + 255) / 256;

    init_kernel<<<(n + 255) / 256, 256, 0, stream>>>(x, ei, deg, counter, flags, n);
    degree_gemm_kernel<<<ngemm + ndeg, 256, 65536, stream>>>(ei, deg, E, x, W, hbuf, n,
                                                             ngemm, flags);
    scan_kernel<<<(n + 255) / 256, 256, 0, stream>>>(deg, dinv, off, cur, counter, n);
    fill_kernel<<<(E + 255) / 256, 256, 0, stream>>>(ei, dinv, cur, slab, E, flags);
    gather_kernel<<<(n + 3) / 4, 256, 0, stream>>>(hbuf, off, deg, slab, dinv,
                                                   b, d_out, n, flags);
}